// Round 1
// baseline (90.830 us; speedup 1.0000x reference)
//
#include <hip/hip_runtime.h>
#include <hip/hip_bf16.h>

// Problem: N=16384 nodes, A=256 anchors, D=32 latdim. All tensors fp32.
// Algebraic collapse of the reference:
//   out[n,:] = dists^T @ M1s + c
//   M1s = (1/A) * embeds[anchor_ids] @ W1      [A, D] fp32 (ws)
//   c   = (1/A) * (sum_{a<A} embeds[a,:]) @ W2 + b  [D] fp32 (ws)
// W1 = W_hidden[0:32,:], W2 = W_hidden[32:64,:]  (W stored [2D, D] row-major)
//
// Roofline: 16 MB dists read + 2 MB out write ≈ 2.9 µs @ 6.3 TB/s. Compute
// 268 MFLOP fp32 ≈ 1.7 µs. Memory-bound target.

#define NN 16384
#define AA 256
#define DD 32

// ---------------- Kernel 1: precompute M1s and c ----------------
// grid = 9 blocks x 256 threads. Blocks 0..7: M1s (32 anchors each). Block 8: c.
__global__ __launch_bounds__(256) void pnn_pre(
    const float* __restrict__ embeds,
    const float* __restrict__ W,
    const float* __restrict__ bvec,
    const int* __restrict__ ids,
    float* __restrict__ M1s,
    float* __restrict__ cvec) {
  const int t = threadIdx.x;
  if (blockIdx.x < 8) {
    // ---- M1s: thread = (anchor_local = t>>3, d-quad dq = t&7) ----
    __shared__ float W1f[DD * DD];  // 32x32 fp32 = 4 KB (W1 rows 0..31)
    for (int idx = t; idx < DD * DD; idx += 256) W1f[idx] = W[idx];
    __syncthreads();
    const int a = blockIdx.x * 32 + (t >> 3);
    const int dq = t & 7;
    const int id = ids[a];
    const float* row = embeds + (size_t)id * DD;
    float4 acc = make_float4(0.f, 0.f, 0.f, 0.f);
    #pragma unroll
    for (int k = 0; k < DD; ++k) {
      const float e = row[k];
      const float4 wv = ((const float4*)W1f)[k * 8 + dq];
      acc.x += e * wv.x; acc.y += e * wv.y; acc.z += e * wv.z; acc.w += e * wv.w;
    }
    const float sc = 1.0f / (float)AA;
    float4 r = make_float4(acc.x * sc, acc.y * sc, acc.z * sc, acc.w * sc);
    ((float4*)(M1s + a * DD))[dq] = r;
  } else {
    // ---- c: column sums of embeds[0:256] then matvec with W2, add b ----
    __shared__ float wred[4][DD];
    __shared__ float esum[DD];
    const int lane = t & 63;
    const int w = t >> 6;
    const float* row = embeds + (size_t)t * DD;  // rows 0..255
    #pragma unroll
    for (int k = 0; k < DD; ++k) {
      float v = row[k];
      #pragma unroll
      for (int off = 32; off >= 1; off >>= 1) v += __shfl_xor(v, off, 64);
      if (lane == 0) wred[w][k] = v;
    }
    __syncthreads();
    if (t < DD) esum[t] = wred[0][t] + wred[1][t] + wred[2][t] + wred[3][t];
    __syncthreads();
    if (t < DD) {
      const int d = t;
      float acc = 0.f;
      #pragma unroll
      for (int k = 0; k < DD; ++k)
        acc += esum[k] * W[(DD + k) * DD + d];  // W2
      cvec[d] = acc * (1.0f / (float)AA) + bvec[d];
    }
  }
}

// ---------------- Kernel 2: out = dists^T @ M1s + c ----------------
// grid = 256 blocks x 512 threads (8 waves). Block owns 64 n-columns.
// Wave w accumulates anchors [32w, 32w+32); lane = n offset (coalesced dists:
// 64 lanes read 64 consecutive floats = 256 B per anchor-row).
//
// v2 changes vs previous best:
//  (a) 32-deep explicit dists prefetch: all 32 global_load_dword issued before
//      the FMA sweep -> 64 KB/CU in flight, hides ~900cy HBM latency (was
//      unroll-4 = only ~8 KB/CU in flight).
//  (b) XOR-swizzled partial buffer: old layout had all 64 lanes of each
//      ds_write_b128 in one 4-bank group (row stride 128 B) = 8x serialization;
//      quad-index swizzle j^(row&7) makes both write and reduce-read
//      conflict-free.
__global__ __launch_bounds__(512) void pnn_main(
    const float* __restrict__ dists,
    const float* __restrict__ M1s,
    const float* __restrict__ cvec,
    float* __restrict__ out) {
  __shared__ float part[8 * 64 * DD];  // 64 KB, float4-quad XOR-swizzled
  const int t = threadIdx.x;
  const int lane = t & 63;
  const int w = t >> 6;
  const int nbase = blockIdx.x * 64;

  float acc[DD];
  #pragma unroll
  for (int d = 0; d < DD; ++d) acc[d] = 0.f;

  // ---- (a) issue all 32 dists loads up front (max memory-level parallelism)
  const float* dcol = dists + (size_t)(w * 32) * NN + nbase + lane;
  float sv[32];
  #pragma unroll
  for (int i = 0; i < 32; ++i) sv[i] = dcol[(size_t)i * NN];  // 256 B/wave each

  // ---- FMA sweep; M1s rows via wave-uniform SGPR address (s_load path)
  #pragma unroll
  for (int i = 0; i < 32; ++i) {
    const int au = __builtin_amdgcn_readfirstlane((w << 5) + i);
    const float4* mrow = (const float4*)(M1s + (au << 5));
    const float s = sv[i];
    #pragma unroll
    for (int j = 0; j < 8; ++j) {
      const float4 m = mrow[j];
      acc[4 * j + 0] += s * m.x;
      acc[4 * j + 1] += s * m.y;
      acc[4 * j + 2] += s * m.z;
      acc[4 * j + 3] += s * m.w;
    }
  }

  // ---- (b) partials -> LDS, quad-index XOR swizzle (conflict-free b128)
  float4* p4 = (float4*)part;
  // row == t (w*64+lane); thread t's quads stored at t*8 + (j ^ (t&7))
  #pragma unroll
  for (int j = 0; j < 8; ++j)
    p4[t * 8 + (j ^ (t & 7))] =
        make_float4(acc[4 * j + 0], acc[4 * j + 1], acc[4 * j + 2], acc[4 * j + 3]);
  __syncthreads();

  // Reduce: thread -> (n_r = t>>3, d-quad dqi = t&7); sum 8 wave partials + c.
  const int n_r = t >> 3;
  const int dqi = t & 7;
  float4 s4 = make_float4(0.f, 0.f, 0.f, 0.f);
  #pragma unroll
  for (int wi = 0; wi < 8; ++wi) {
    const int r = wi * 64 + n_r;                    // r & 7 == n_r & 7
    const float4 v = p4[r * 8 + (dqi ^ (n_r & 7))]; // un-swizzle
    s4.x += v.x; s4.y += v.y; s4.z += v.z; s4.w += v.w;
  }
  const float4 cv = *(const float4*)(cvec + dqi * 4);
  s4.x += cv.x; s4.y += cv.y; s4.z += cv.z; s4.w += cv.w;

  *(float4*)(out + (size_t)(nbase + n_r) * DD + dqi * 4) = s4;
}

extern "C" void kernel_launch(void* const* d_in, const int* in_sizes, int n_in,
                              void* d_out, int out_size, void* d_ws, size_t ws_size,
                              hipStream_t stream) {
  const float* embeds = (const float*)d_in[0];  // [N, D]
  const float* dists  = (const float*)d_in[1];  // [A, N]
  const float* W      = (const float*)d_in[2];  // [2D, D]
  const float* bvec   = (const float*)d_in[3];  // [D]
  const int* ids      = (const int*)d_in[4];    // [A]
  float* out = (float*)d_out;                   // [N, D]

  float* wsf = (float*)d_ws;
  float* M1s = wsf;             // 256*32 fp32
  float* cvec = wsf + AA * DD;  // 32 fp32

  pnn_pre<<<9, 256, 0, stream>>>(embeds, W, bvec, ids, M1s, cvec);
  pnn_main<<<256, 512, 0, stream>>>(dists, M1s, cvec, out);
}